// Round 1
// 12769.517 us; speedup vs baseline: 1.0329x; 1.0329x over previous
//
#include <hip/hip_runtime.h>

// BRITS fused persistent-RNN kernel for MI355X (gfx950) — v2 "no-spill".
//
// Theory of v1's 12.8 ms: 192 weight floats/lane vs VGPR_Count=128 -> weight
// arrays spilled to scratch; FETCH_SIZE=15.4 GB (120x algorithmic traffic) was
// per-thread scratch re-read every timestep; serial dot chains stalled on the
// reloads (VALUBusy 10.6%).
//
// v2 structure (512 threads = 8 waves, 2 sequences/block, grid 256 = 1 block/CU):
//  - Gate weights [Wih | Whh] split over ALL 8 waves x 2 K-halves:
//    lane (w,l): row r=w*32+(l&31), half h=l>>5 -> 96 floats/lane in registers.
//    Halves combined with one __shfl_xor(g,32). Fits under a 128-VGPR cap.
//  - Whr/Wfr/Wdh/Wwc (80 KB) in LDS, XOR-swizzled rows (slot = k4 ^ (lane&7))
//    so per-lane-row ds_read_b128 is bank-conflict-free.
//  - 3 raw barriers/step (s_waitcnt lgkmcnt(0) + s_barrier), NOT __syncthreads:
//    avoids vmcnt(0) drains of pred stores / prefetch at every phase.
//  - Prefetch split: issue global x,m(t+1) in phase A, ds_write in phase B.
//  - xh -> xc -> zh chain runs inside ONE wave (w0: seq0, w1: seq1); the
//    cross-lane hop goes through LDS within the wave (no barrier needed).

constexpr int NB = 256;   // batch
constexpr int NT = 1024;  // time
constexpr int ND = 64;    // features D (= H)
constexpr int NG = 256;   // 4*H gate width
constexpr int K2 = 128;   // 2*D

__device__ __forceinline__ float sgm(float v){ return 1.0f/(1.0f+__expf(-v)); }
__device__ __forceinline__ float tnh(float v){
  float a = fabsf(v);
  float e = __expf(-2.0f*a);
  float t = (1.0f-e)/(1.0f+e);
  return v < 0.0f ? -t : t;
}

// raw barrier: drain own LDS writes, then s_barrier. No vmcnt(0) drain.
__device__ __forceinline__ void bar(){
  asm volatile("s_waitcnt lgkmcnt(0)" ::: "memory");
  __builtin_amdgcn_s_barrier();
}

// y = sum_k W[row][k]*act[k], K=64. wrow = &Wsw[row*64]; weights stored with
// slot = k4 ^ (row&7) (conflict-free b128); act is a wave-uniform broadcast.
__device__ __forceinline__ float dot64_sw(const float* wrow, int swl,
                                          const float* act){
  float a0=0.f,a1=0.f,a2=0.f,a3=0.f;
  #pragma unroll
  for (int k4=0;k4<16;++k4){
    const float4 wv = *(const float4*)(wrow + ((k4^swl)<<2));
    const float4 av = *(const float4*)(act + (k4<<2));
    a0=fmaf(wv.x,av.x,a0); a1=fmaf(wv.y,av.y,a1);
    a2=fmaf(wv.z,av.z,a2); a3=fmaf(wv.w,av.w,a3);
  }
  return (a0+a1)+(a2+a3);
}

// K=128 version: act = [actA(64) ; actB(64)] (Wwc: [gamma_x ; m]).
__device__ __forceinline__ float dot128_sw(const float* wrow, int swl,
                                           const float* actA, const float* actB){
  float a0=0.f,a1=0.f,a2=0.f,a3=0.f;
  #pragma unroll
  for (int k4=0;k4<32;++k4){
    const float4 wv = *(const float4*)(wrow + ((k4^swl)<<2));
    const float4 av = (k4<16) ? *(const float4*)(actA + (k4<<2))
                              : *(const float4*)(actB + (((k4-16))<<2));
    a0=fmaf(wv.x,av.x,a0); a1=fmaf(wv.y,av.y,a1);
    a2=fmaf(wv.z,av.z,a2); a3=fmaf(wv.w,av.w,a3);
  }
  return (a0+a1)+(a2+a3);
}

// register-weight dots; arrays indexed only by unrolled constants (keep SROA happy)
#define GATE_DOT(res, ACT) do{                                           \
    float a0=0.f,a1=0.f,a2=0.f,a3=0.f;                                   \
    _Pragma("unroll")                                                    \
    for (int k=0;k<64;k+=4){                                             \
      const float4 av = *(const float4*)((ACT)+k);                       \
      a0=fmaf(wg_ih[k  ],av.x,a0); a1=fmaf(wg_ih[k+1],av.y,a1);          \
      a2=fmaf(wg_ih[k+2],av.z,a2); a3=fmaf(wg_ih[k+3],av.w,a3);          \
    }                                                                    \
    res = (a0+a1)+(a2+a3); }while(0)

#define PHH_DOT(res, ACT) do{                                            \
    float a0=0.f,a1=0.f,a2=0.f,a3=0.f;                                   \
    _Pragma("unroll")                                                    \
    for (int k=0;k<32;k+=4){                                             \
      const float4 av = *(const float4*)((ACT)+k);                       \
      a0=fmaf(wg_hh[k  ],av.x,a0); a1=fmaf(wg_hh[k+1],av.y,a1);          \
      a2=fmaf(wg_hh[k+2],av.z,a2); a3=fmaf(wg_hh[k+3],av.w,a3);          \
    }                                                                    \
    res = (a0+a1)+(a2+a3); }while(0)

__global__ __launch_bounds__(512, 2) void brits_fused(
    const float* __restrict__ x_g, const float* __restrict__ m_g,
    const float* __restrict__ Wih_g, const float* __restrict__ Whh_g,
    const float* __restrict__ bih_g, const float* __restrict__ bhh_g,
    const float* __restrict__ Wdh_g, const float* __restrict__ bdh_g,
    const float* __restrict__ wdx_g, const float* __restrict__ bdx_g,
    const float* __restrict__ Whr_g, const float* __restrict__ bhr_g,
    const float* __restrict__ Wfr_g, const float* __restrict__ bfr_g,
    const float* __restrict__ Wwc_g, const float* __restrict__ bwc_g,
    float* __restrict__ out0, float* __restrict__ pred)
{
  const int tid = threadIdx.x;
  const int l   = tid & 63;                                   // lane
  const int w   = __builtin_amdgcn_readfirstlane(tid >> 6);   // wave 0..7 (SGPR)
  const int h   = l >> 5;                                     // K-half 0/1
  const int r   = w*32 + (l & 31);                            // gate row 0..255
  const int swl = l & 7;                                      // LDS swizzle key
  const int bid = blockIdx.x;
  const int dir = bid >> 7;                                   // 0=fwd, 1=bwd
  const int pair = bid & 127;
  const int b0 = pair*2, b1 = pair*2+1;

  const float* Wih_d = Wih_g + (size_t)dir*NG*K2;
  const float* Whh_d = Whh_g + (size_t)dir*NG*ND;
  const float* bih_d = bih_g + dir*NG;
  const float* bhh_d = bhh_g + dir*NG;
  const float* Wdh_d = Wdh_g + dir*ND*ND;
  const float* bdh_d = bdh_g + dir*ND;
  const float* wdx_d = wdx_g + dir*ND;
  const float* bdx_d = bdx_g + dir*ND;
  const float* Whr_d = Whr_g + dir*ND*ND;
  const float* bhr_d = bhr_g + dir*ND;
  const float* Wfr_d = Wfr_g + dir*ND*ND;
  const float* bfr_d = bfr_g + dir*ND;
  const float* Wwc_d = Wwc_g + dir*ND*K2;
  const float* bwc_d = bwc_g + dir*ND;

  // ---- LDS: weights (swizzled rows) + tiny activation staging (~88 KB) ----
  __shared__ __align__(16) float Whr_sw[64*64];
  __shared__ __align__(16) float Wfr_sw[64*64];   // diag zeroed at staging
  __shared__ __align__(16) float Wdh_sw[64*64];
  __shared__ __align__(16) float Wwc_sw[64*128];
  __shared__ __align__(16) float h_s [2][ND];     // h(t)
  __shared__ __align__(16) float hd_s[2][ND];     // h(t)*gamma_h(t)
  __shared__ __align__(16) float xc_s[2][ND];
  __shared__ __align__(16) float cc_s[2][ND];
  __shared__ __align__(16) float dl_s[2][ND];     // delta(t+1)
  __shared__ __align__(16) float gx_s[2][ND];     // gamma_x(t+1)
  __shared__ __align__(16) float gh_s[2][ND];     // gamma_h(t+1)
  __shared__ __align__(16) float al_s[2][ND];     // alpha(t)
  __shared__ __align__(16) float gt_s[2][NG];     // gate preactivations
  __shared__ __align__(16) float xb_s[2][2][ND];  // x double-buffer [parity][seq]
  __shared__ __align__(16) float mb_s[2][2][ND];  // m double-buffer

  // ---- stage small weight matrices into swizzled LDS (all 8 waves) ----
  {
    #pragma unroll
    for (int q=0;q<2;++q){
      const int k4 = 2*w + q;           // 0..15 across waves
      float4 v;
      v = *(const float4*)(Whr_d + l*ND + 4*k4);
      *(float4*)(Whr_sw + l*64 + ((k4^swl)<<2)) = v;
      v = *(const float4*)(Wdh_d + l*ND + 4*k4);
      *(float4*)(Wdh_sw + l*64 + ((k4^swl)<<2)) = v;
      v = *(const float4*)(Wfr_d + l*ND + 4*k4);
      const int c = 4*k4;               // zero the diagonal of feat_reg
      if (c   == l) v.x = 0.f;
      if (c+1 == l) v.y = 0.f;
      if (c+2 == l) v.z = 0.f;
      if (c+3 == l) v.w = 0.f;
      *(float4*)(Wfr_sw + l*64 + ((k4^swl)<<2)) = v;
    }
    #pragma unroll
    for (int q=0;q<4;++q){
      const int k4 = 4*w + q;           // 0..31 across waves
      float4 v = *(const float4*)(Wwc_d + l*K2 + 4*k4);
      *(float4*)(Wwc_sw + l*128 + ((k4^swl)<<2)) = v;
    }
  }

  // ---- gate weights into registers: 96 floats/lane ----
  float wg_ih[64];   // Wih[r][64h .. 64h+63]
  float wg_hh[32];   // Whh[r][32h .. 32h+31]
  #pragma unroll
  for (int k=0;k<64;k+=4){
    const float4 v = *(const float4*)(Wih_d + (size_t)r*K2 + h*64 + k);
    wg_ih[k]=v.x; wg_ih[k+1]=v.y; wg_ih[k+2]=v.z; wg_ih[k+3]=v.w;
  }
  #pragma unroll
  for (int k=0;k<32;k+=4){
    const float4 v = *(const float4*)(Whh_d + (size_t)r*ND + h*32 + k);
    wg_hh[k]=v.x; wg_hh[k+1]=v.y; wg_hh[k+2]=v.z; wg_hh[k+3]=v.w;
  }
  const float gbias = bih_d[r] + bhh_d[r];   // added by the h==0 writer lane

  // per-role scalars
  float bhr_l=0.f, bfr_l=0.f, wdx_l=0.f, bdx_l=0.f, bdh_l=0.f, bwc_l=0.f;
  const float* whr_row = Whr_sw + l*64;
  const float* wfr_row = Wfr_sw + l*64;
  const float* wdh_row = Wdh_sw + l*64;
  const float* wwc_row = Wwc_sw + l*128;
  if (w < 2){ bhr_l = bhr_d[l]; bfr_l = bfr_d[l]; wdx_l = wdx_d[l]; bdx_l = bdx_d[l]; }
  if (w==4 || w==5){ bdh_l = bdh_d[l]; }
  if (w>=6){ bwc_l = bwc_d[l]; }

  float cst = 0.f;          // LSTM cell state (w0: seq0 unit l / w1: seq1)
  float dlt = 0.f;          // delta carry    (w0/w1)
  float xr  = 0.f, mr = 0.f;// prefetch regs  (w2/w3)

  const size_t NBTD  = (size_t)NB*NT*ND;
  const size_t plane0 = (size_t)(0+dir)*NBTD;   // ch
  const size_t plane2 = (size_t)(2+dir)*NBTD;   // zh
  const size_t plane4 = (size_t)(4+dir)*NBTD;   // xh

  // ---- prologue: zero state, load t=0, gamma_x(0), alpha(0) ----
  if (w == 0){
    h_s[0][l]=0.f; h_s[1][l]=0.f; hd_s[0][l]=0.f; hd_s[1][l]=0.f;
  }
  if (w==2 || w==3){
    const int s = w-2;
    const int bbs = s ? b1 : b0;
    const int t0 = dir ? (NT-1) : 0;
    const size_t ib = ((size_t)bbs*NT + t0)*ND + l;
    xb_s[0][s][l] = x_g[ib];
    mb_s[0][s][l] = m_g[ib];
  }
  if (w < 2){
    gx_s[w][l] = __expf(-fmaxf(0.f, bdx_l));   // gamma_x(0): delta=0
  }
  bar();
  if (w >= 6){                                  // alpha(0)
    const int s = w-6;
    al_s[s][l] = sgm(bwc_l + dot128_sw(wwc_row, swl, &gx_s[s][0], &mb_s[0][s][0]));
  }
  bar();

  for (int t=0; t<NT; ++t){
    const int cur = t & 1;
    const int nxt = cur ^ 1;
    const int tm  = dir ? (NT-1-t) : t;

    // ======== Phase A ========
    // all waves: Whh*hdec(t) gate partials (register weights, broadcast acts)
    float phh0, phh1;
    PHH_DOT(phh0, &hd_s[0][h*32]);
    PHH_DOT(phh1, &hd_s[1][h*32]);

    if (w < 2){
      // sequence-owner wave: xh -> xc -> (LDS hop, same wave) -> zh -> ch/cc
      const int s = w;
      const int bbs = s ? b1 : b0;
      const size_t ob = ((size_t)bbs*NT + tm)*ND + l;
      const float xh = bhr_l + dot64_sw(whr_row, swl, &h_s[s][0]);
      pred[plane4 + ob] = xh;
      const float mm = mb_s[cur][s][l];
      const float xx = xb_s[cur][s][l];
      const float xc = mm*xx + (1.f-mm)*xh;
      xc_s[s][l] = xc;
      // delta(t+1)/gamma_x(t+1) (pointwise, feeds B:gamma_h and C:alpha)
      dlt = 1.0f + (1.0f-mm)*dlt;
      dl_s[s][l] = dlt;
      gx_s[s][l] = __expf(-fmaxf(0.f, fmaf(dlt, wdx_l, bdx_l)));
      // zh needs all lanes' xc: same-wave LDS round-trip (compiler lgkmcnt)
      const float zh = bfr_l + dot64_sw(wfr_row, swl, &xc_s[s][0]);
      pred[plane2 + ob] = zh;
      const float a  = al_s[s][l];
      const float ch = a*zh + (1.f-a)*xh;
      const float cc = mm*xx + (1.f-mm)*ch;
      cc_s[s][l] = cc;
      pred[plane0 + ob] = ch;
      atomicAdd(&out0[ob], 0.5f*cc);            // mean over the two directions
    } else if (w < 4){
      // issue x,m(t+1) loads; land them in LDS next phase (latency cover)
      if (t+1 < NT){
        const int s = w-2;
        const int bbs = s ? b1 : b0;
        const int tn = dir ? (NT-2-t) : (t+1);
        const size_t ib = ((size_t)bbs*NT + tn)*ND + l;
        xr = x_g[ib];
        mr = m_g[ib];
      }
    }
    bar();

    // ======== Phase B ========
    {
      // gates, both sequences; K-halves combined via shfl_xor(32)
      float g0, g1;
      GATE_DOT(g0, h ? &mb_s[cur][0][0] : &cc_s[0][0]);
      GATE_DOT(g1, h ? &mb_s[cur][1][0] : &cc_s[1][0]);
      g0 += phh0;
      g1 += phh1;
      g0 += __shfl_xor(g0, 32, 64);
      g1 += __shfl_xor(g1, 32, 64);
      if (h == 0){
        gt_s[0][r] = g0 + gbias;
        gt_s[1][r] = g1 + gbias;
      }
    }
    if (w==2 || w==3){
      if (t+1 < NT){
        const int s = w-2;
        xb_s[nxt][s][l] = xr;
        mb_s[nxt][s][l] = mr;
      }
    } else if ((w==4 || w==5) && (t+1 < NT)){
      const int s = w-4;                        // gamma_h(t+1) from delta(t+1)
      gh_s[s][l] = __expf(-fmaxf(0.f, bdh_l + dot64_sw(wdh_row, swl, &dl_s[s][0])));
    }
    bar();

    // ======== Phase C ========
    if (w < 2){
      const int s = w;                          // LSTM cell update
      const float gi = gt_s[s][l];
      const float gf = gt_s[s][64+l];
      const float gg = gt_s[s][128+l];
      const float go = gt_s[s][192+l];
      cst = sgm(gf)*cst + sgm(gi)*tnh(gg);
      const float hn = sgm(go)*tnh(cst);
      h_s[s][l]  = hn;
      hd_s[s][l] = hn * gh_s[s][l];             // gamma_h(t+1) from B
    } else if (w >= 6 && (t+1 < NT)){
      const int s = w-6;                        // alpha(t+1) = sgm(Wwc.[gx;m]+bwc)
      al_s[s][l] = sgm(bwc_l + dot128_sw(wwc_row, swl, &gx_s[s][0], &mb_s[nxt][s][0]));
    }
    bar();
  }
}

extern "C" void kernel_launch(void* const* d_in, const int* in_sizes, int n_in,
                              void* d_out, int out_size, void* d_ws, size_t ws_size,
                              hipStream_t stream) {
  (void)in_sizes; (void)n_in; (void)d_ws; (void)ws_size; (void)out_size;
  const float* x   = (const float*)d_in[0];
  const float* m   = (const float*)d_in[1];
  const float* Wih = (const float*)d_in[2];
  const float* Whh = (const float*)d_in[3];
  const float* bih = (const float*)d_in[4];
  const float* bhh = (const float*)d_in[5];
  const float* Wdh = (const float*)d_in[6];
  const float* bdh = (const float*)d_in[7];
  const float* wdx = (const float*)d_in[8];
  const float* bdx = (const float*)d_in[9];
  const float* Whr = (const float*)d_in[10];
  const float* bhr = (const float*)d_in[11];
  const float* Wfr = (const float*)d_in[12];
  const float* bfr = (const float*)d_in[13];
  const float* Wwc = (const float*)d_in[14];
  const float* bwc = (const float*)d_in[15];

  float* out  = (float*)d_out;                       // [B,T,D,1] mean imputation
  float* pred = out + (size_t)NB*NT*ND;              // [6,B,T,D,1]

  // out0 is accumulated by both directions via atomicAdd -> zero it first
  // (d_out is re-poisoned before every timed launch).
  hipMemsetAsync(out, 0, (size_t)NB*NT*ND*sizeof(float), stream);

  brits_fused<<<dim3(256), dim3(512), 0, stream>>>(
      x, m, Wih, Whh, bih, bhh, Wdh, bdh, wdx, bdx,
      Whr, bhr, Wfr, bfr, Wwc, bwc, out, pred);
}